// Round 12
// baseline (2862.269 us; speedup 1.0000x reference)
//
#include <hip/hip_runtime.h>
#include <hip/hip_bf16.h>
#include <stdint.h>

// Persistent time-skewed acoustic FD, round 12.
// vs round 11 (2.57ms): (1) pre-scaled coefficients Cb1/Cb2/Cq1/Cq2 cut
// packed-op count ~16%; (2) refresh skips never-read deep-halo rows
// (margin>28) and the all-zero w=0 load; (3) last window skips publish.
// Structure/sync/stencil selects identical to round 11.

#define NXd 512
#define NZd 512
#define NTd 1000
#define Sd  2
#define Rd  512
#define C1f 1.125f
#define C2f (-1.0f/24.0f)
#define CVXf 1e-4f              // DT/DX
#define SRC_AMPf 1e-5f          // DT/(DX*DZ)

#define TZ 32
#define TX 64
#define KSTEPS 7
#define NWIN 143                // 142*7 + 6 = 1000
#define Hz 32
#define Hx 32
#define RLZ 96                  // TZ + 2*Hz
#define RLX 128                 // TX + 2*Hx
#define ZB 3                    // rows per thread
#define NZBLK 32                // RLZ/ZB
#define NTHR 1024               // NZBLK*32

#define NN  (NZd*NXd)
#define FSZ (Sd*NN)
#define BUF_SZ (3*FSZ)
#define FLAG_OFF (2*BUF_SZ)
#define BAR_OFF  (2*BUF_SZ + 32)
#define WS_NEED_FLOATS (2*BUF_SZ + 32 + 160)
#define WS_NEED_BYTES ((size_t)WS_NEED_FLOATS * 4)

typedef float vf4 __attribute__((ext_vector_type(4)));

__device__ __forceinline__ vf4 ld4(const float* p) { return *(const vf4*)p; }
__device__ __forceinline__ void st4(float* p, vf4 v) { *(vf4*)p = v; }

// write-through 16B store: lands at the coherence point, no dirty L2 line.
__device__ __forceinline__ void st4_wt(float* p, vf4 v) {
    asm volatile("global_store_dwordx4 %0, %1, off sc0 sc1" :: "v"(p), "v"(v) : "memory");
}
__device__ __forceinline__ void st1_wt(float* p, float v) {
    asm volatile("global_store_dword %0, %1, off sc0 sc1" :: "v"(p), "v"(v) : "memory");
}
__device__ __forceinline__ void sth_wt(void* p, unsigned short bits) {
    unsigned u = bits;
    asm volatile("global_store_short %0, %1, off sc0 sc1" :: "v"(p), "v"(u) : "memory");
}

// DPP wave shifts (verified round 5): wave_shr:1 (0x138) = value from lane-1,
// wave_shl:1 (0x130) = value from lane+1. bound_ctrl -> 0 at wave edge.
__device__ __forceinline__ float sh_up1(float v) {
    return __int_as_float(__builtin_amdgcn_update_dpp(
        0, __float_as_int(v), 0x138, 0xF, 0xF, true));
}
__device__ __forceinline__ float sh_dn1(float v) {
    return __int_as_float(__builtin_amdgcn_update_dpp(
        0, __float_as_int(v), 0x130, 0xF, 0xF, true));
}

__global__ void detect_k(const uint32_t* __restrict__ vp_raw, int* __restrict__ flag) {
    int lane = threadIdx.x;
    uint32_t u = vp_raw[lane];
    int hb = (u >> 8) & 0xFF;
    int is_exp = (hb == 0x44 || hb == 0x45) ? 1 : 0;
    unsigned long long m = __ballot(is_exp);
    if (lane == 0) *flag = (__popcll(m) >= 48) ? 1 : 0;
}

__device__ __forceinline__ float load_in(const void* p, int i, int bf) {
    return bf ? __bfloat162float(((const __hip_bfloat16*)p)[i])
              : ((const float*)p)[i];
}

// Monotonic grid barrier (round-7 verified): relaxed tree arrival (data is
// already at coherence point), acquire fence (buffer_inv only) on wake.
__device__ __forceinline__ void gbar(unsigned* __restrict__ bar, int wg, int w) {
    __syncthreads();
    if (threadIdx.x == 0) {
        unsigned* gcnt = bar + (wg & 7) * 16;
        unsigned* mcnt = bar + 128;
        unsigned* gen  = bar + 144;
        unsigned tgt = (unsigned)(w + 1);
        unsigned a = __hip_atomic_fetch_add(gcnt, 1u, __ATOMIC_RELAXED, __HIP_MEMORY_SCOPE_AGENT);
        if (a == 32u * tgt - 1u) {
            unsigned m = __hip_atomic_fetch_add(mcnt, 1u, __ATOMIC_RELAXED, __HIP_MEMORY_SCOPE_AGENT);
            if (m == 8u * tgt - 1u) {
                __hip_atomic_store(gen, tgt, __ATOMIC_RELEASE, __HIP_MEMORY_SCOPE_AGENT);
            }
        }
        for (int it = 0; it < 300000; ++it) {
            if (__hip_atomic_load(gen, __ATOMIC_RELAXED, __HIP_MEMORY_SCOPE_AGENT) >= tgt) break;
            __builtin_amdgcn_s_sleep(2);
        }
        __builtin_amdgcn_fence(__ATOMIC_ACQUIRE, "agent");
    }
    __syncthreads();
}

__global__ __launch_bounds__(NTHR) void persist_k(float* __restrict__ ws,
        void* __restrict__ out, const void* __restrict__ vp,
        const void* __restrict__ rho, const void* __restrict__ damp,
        const void* __restrict__ wav,
        const int* __restrict__ sxp, const int* __restrict__ szp,
        const int* __restrict__ rxp, const int* __restrict__ rzp) {
    __shared__ float lp [RLZ*RLX];           // 48 KB: all p rows
    __shared__ float lvz[RLZ*RLX];           // 48 KB: all vz rows
    __shared__ float lwv[KSTEPS];            // window waveform samples
    // 96+ KB -> 1 WG/CU, co-residency for the barrier

    const int tid  = threadIdx.x;
    const int xg   = tid & 31;
    const int zblk = tid >> 5;               // 0..31
    const int zb0  = zblk * ZB;
    const int xo   = xg * 4;

    const int wg  = blockIdx.x;
    const int xcd = wg & 7;
    const int ii  = wg >> 3;
    const int s   = ii >> 4;
    const int loc = ii & 15;
    const int tz0 = ((xcd >> 1) * 4 + (loc >> 2)) * TZ;
    const int tx0 = ((xcd & 1) * 4 + (loc & 3)) * TX;
    const int bf  = *(const int*)(ws + FLAG_OFF);
    unsigned* bar = (unsigned*)(ws + BAR_OFF);

    const int rxv = (tid < Rd) ? rxp[tid] : 0;
    const int rzv = (tid < Rd) ? rzp[tid] : -1000;
    const bool own = (tid < Rd) && (rzv >= tz0 && rzv < tz0 + TZ &&
                                    rxv >= tx0 && rxv < tx0 + TX);
    const int lrcv = (rzv - tz0 + Hz) * RLX + (rxv - tx0 + Hx);
    const int sxv = sxp[s], szv = szp[s];

    // clamped cross-block row indices (region edges tolerate garbage)
    const int zPm  = (zb0 - 1 < 0) ? 0 : zb0 - 1;
    const int zPn0 = (zb0 + ZB     > RLZ - 1) ? RLZ - 1 : zb0 + ZB;
    const int zPn1 = (zb0 + ZB + 1 > RLZ - 1) ? RLZ - 1 : zb0 + ZB + 1;
    const int zVm2 = (zb0 - 2 < 0) ? 0 : zb0 - 2;
    const int zVm1 = zPm;
    const int zVn0 = zPn0;

    const vf4 zero4 = {0.f, 0.f, 0.f, 0.f};

    // ---- coefficients: loaded once, pre-scaled by C1/C2, register-resident
    vf4 Ca[ZB], Cb1[ZB], Cb2[ZB], Cq1[ZB], Cq2[ZB];
    #pragma unroll
    for (int r = 0; r < ZB; ++r) {
        int gz = tz0 - Hz + zb0 + r;
        int gx = tx0 - Hx + xo;
        vf4 a = zero4, b1 = zero4, b2 = zero4, q1 = zero4, q2 = zero4;
        if (gz >= 0 && gz < NZd) {
            #pragma unroll
            for (int c = 0; c < 4; ++c) {
                int x = gx + c;
                if (x >= 0 && x < NXd) {
                    int gi = gz * NXd + x;
                    float v  = load_in(vp,  gi, bf);
                    float rr = load_in(rho, gi, bf);
                    float d  = load_in(damp, gi, bf);
                    float cb = d * (CVXf / rr);
                    float cq = d * (CVXf * rr * v * v);
                    ((float*)&a)[c]  = d;
                    ((float*)&b1)[c] = cb * C1f;
                    ((float*)&b2)[c] = cb * C2f;
                    ((float*)&q1)[c] = cq * C1f;
                    ((float*)&q2)[c] = cq * C2f;
                }
            }
        }
        Ca[r] = a; Cb1[r] = b1; Cb2[r] = b2; Cq1[r] = q1; Cq2[r] = q2;
    }

    vf4 Pv[ZB], Vx[ZB], Vz[ZB];
    #pragma unroll
    for (int r = 0; r < ZB; ++r) { Pv[r] = zero4; Vx[r] = zero4; Vz[r] = zero4; }

    for (int w = 0; w < NWIN; ++w) {
        const int kk = (NTd - w * KSTEPS < KSTEPS) ? (NTd - w * KSTEPS) : KSTEPS;
        const float* bR = ws + (w & 1) * BUF_SZ;
        float*       bW = ws + ((w + 1) & 1) * BUF_SZ;
        const float* rp  = bR + s * NN;
        const float* rvx = bR + FSZ + s * NN;
        const float* rvz = bR + 2 * FSZ + s * NN;

        // ---- waveform samples for this window -> LDS
        if (tid < kk) lwv[tid] = load_in(wav, s * NTd + w * KSTEPS + tid, bf);

        // ---- halo refresh. Skips: w==0 (state known zero, registers are the
        // state), z-rows with state-margin > 28 (rows 0..3, 92..95 -- provably
        // never read: V-active blocks reach down only to row 4).
        #pragma unroll
        for (int r = 0; r < ZB; ++r) {
            int z = zb0 + r;
            int gz = tz0 - Hz + z;
            int gx = tx0 - Hx + xo;
            bool intile = (z >= Hz && z < Hz + TZ && xo >= Hx && xo < Hx + TX);
            if (!intile) {
                bool in = (w > 0) && (z >= 4) && (z < RLZ - 4) &&
                          (gz >= 0) && (gz < NZd) && (gx >= 0) && (gx < NXd);
                if (in) {
                    int gi = gz * NXd + gx;
                    Pv[r] = ld4(rp + gi); Vx[r] = ld4(rvx + gi); Vz[r] = ld4(rvz + gi);
                } else if (w == 0) {
                    Pv[r] = zero4; Vx[r] = zero4; Vz[r] = zero4;
                }
            }
            st4(lp + z * RLX + xo, Pv[r]);
        }
        __syncthreads();

        for (int j = 0; j < kk; ++j) {
            const float wv = lwv[j] * SRC_AMPf;

            const int mV = 4 * (kk - 1 - j) + 2;
            const int mP = mV - 2;
            const bool actV = (zb0 + ZB > Hz - mV) && (zb0 < Hz + TZ + mV);
            const bool actP = (zb0 + ZB > Hz - mP) && (zb0 < Hz + TZ + mP);

            // ---------- V phase: vx,vz <- Ca*v + Cb1*d1 + Cb2*d2  [packed]
            if (actV) {
                vf4 pPm  = ld4(lp + zPm  * RLX + xo);
                vf4 pNx0 = ld4(lp + zPn0 * RLX + xo);
                vf4 pNx1 = ld4(lp + zPn1 * RLX + xo);
                #pragma unroll
                for (int r = 0; r < ZB; ++r) {
                    vf4 c = Pv[r];
                    float pmw = sh_up1(c.w);
                    float ppx = sh_dn1(c.x);
                    float ppy = sh_dn1(c.y);
                    vf4 xm1 = __builtin_shufflevector(c, c, 0, 0, 1, 2); xm1.x = pmw;
                    vf4 xp1 = __builtin_shufflevector(c, c, 1, 2, 3, 3); xp1.w = ppx;
                    vf4 xp2 = __builtin_shufflevector(c, c, 2, 3, 3, 3); xp2.z = ppx; xp2.w = ppy;
                    vf4 pzm = (r == 0) ? pPm : Pv[(r == 0) ? 0 : r - 1];
                    vf4 pz1 = (r == ZB-1) ? pNx0 : Pv[(r == ZB-1) ? ZB-1 : r + 1];
                    vf4 pz2 = (r == ZB-2) ? pNx0 : ((r == ZB-1) ? pNx1 : Pv[(r >= ZB-2) ? ZB-1 : r + 2]);
                    vf4 dx1 = xp1 - c,   dx2 = xp2 - xm1;
                    vf4 dz1 = pz1 - c,   dz2 = pz2 - pzm;
                    vf4 nvx = Ca[r] * Vx[r];
                    nvx += Cb1[r] * dx1;
                    nvx += Cb2[r] * dx2;
                    vf4 nvz = Ca[r] * Vz[r];
                    nvz += Cb1[r] * dz1;
                    nvz += Cb2[r] * dz2;
                    Vx[r] = nvx; Vz[r] = nvz;
                    st4(lvz + (zb0 + r) * RLX + xo, nvz);
                }
            }
            __syncthreads();

            // ---------- P phase: p <- Ca*p + Cq1*(db1x+db1z) + Cq2*(db2x+db2z)
            if (actP) {
                vf4 vm2 = ld4(lvz + zVm2 * RLX + xo);
                vf4 vm1 = ld4(lvz + zVm1 * RLX + xo);
                vf4 vn0 = ld4(lvz + zVn0 * RLX + xo);
                #pragma unroll
                for (int r = 0; r < ZB; ++r) {
                    vf4 cx = Vx[r], cz = Vz[r];
                    float vmz = sh_up1(cx.z);
                    float vmw = sh_up1(cx.w);
                    float vpx = sh_dn1(cx.x);
                    vf4 xm1 = __builtin_shufflevector(cx, cx, 0, 0, 1, 2); xm1.x = vmw;
                    vf4 xp1 = __builtin_shufflevector(cx, cx, 1, 2, 3, 3); xp1.w = vpx;
                    vf4 xm2 = __builtin_shufflevector(cx, cx, 0, 0, 0, 1); xm2.x = vmz; xm2.y = vmw;
                    vf4 zm2 = (r == 0) ? vm2 : ((r == 1) ? vm1 : Vz[(r >= 2) ? r - 2 : 0]);
                    vf4 zm1 = (r == 0) ? vm1 : Vz[(r == 0) ? 0 : r - 1];
                    vf4 zp1 = (r == ZB-1) ? vn0 : Vz[(r == ZB-1) ? ZB-1 : r + 1];
                    vf4 d1 = (cx - xm1) + (cz - zm1);
                    vf4 d2 = (xp1 - xm2) + (zp1 - zm2);
                    vf4 np = Ca[r] * Pv[r];
                    np += Cq1[r] * d1;
                    np += Cq2[r] * d2;
                    int gz = tz0 - Hz + zb0 + r;
                    if (gz == szv) {
                        int dcol = sxv - (tx0 - Hx + xo);
                        if      (dcol == 0) np.x += wv;
                        else if (dcol == 1) np.y += wv;
                        else if (dcol == 2) np.z += wv;
                        else if (dcol == 3) np.w += wv;
                    }
                    Pv[r] = np;
                    st4(lp + (zb0 + r) * RLX + xo, np);
                }
            }
            __syncthreads();

            if (own) {
                float val = lp[lrcv];
                int oi = (s * NTd + (w * KSTEPS + j)) * Rd + tid;
                if (bf) {
                    __hip_bfloat16 h = __float2bfloat16(val);
                    unsigned short bits; __builtin_memcpy(&bits, &h, 2);
                    sth_wt((__hip_bfloat16*)out + oi, bits);
                } else {
                    st1_wt((float*)out + oi, val);
                }
            }
        }

        // ---- publish tile interior (write-through: no dirty L2 at barrier);
        // skipped at the last window (nobody reads it)
        if (w < NWIN - 1) {
            float* wp  = bW + s * NN;
            float* wvx = bW + FSZ + s * NN;
            float* wvz = bW + 2 * FSZ + s * NN;
            #pragma unroll
            for (int r = 0; r < ZB; ++r) {
                int z = zb0 + r;
                if (z >= Hz && z < Hz + TZ && xo >= Hx && xo < Hx + TX) {
                    int gi = (tz0 - Hz + z) * NXd + (tx0 - Hx + xo);
                    st4_wt(wp + gi, Pv[r]);
                    st4_wt(wvx + gi, Vx[r]);
                    st4_wt(wvz + gi, Vz[r]);
                }
            }
            gbar(bar, wg, w);
        }
    }
}

extern "C" void kernel_launch(void* const* d_in, const int* in_sizes, int n_in,
                              void* d_out, int out_size, void* d_ws, size_t ws_size,
                              hipStream_t stream) {
    if (ws_size < WS_NEED_BYTES) return;
    float* ws = (float*)d_ws;
    const void* vp   = d_in[0];
    const void* rho  = d_in[1];
    const void* damp = d_in[2];
    const void* wav  = d_in[3];
    const int* src_x = (const int*)d_in[4];
    const int* src_z = (const int*)d_in[5];
    const int* rcv_x = (const int*)d_in[6];
    const int* rcv_z = (const int*)d_in[7];

    hipMemsetAsync(ws, 0, WS_NEED_BYTES, stream);
    detect_k<<<1, 64, 0, stream>>>((const uint32_t*)vp, (int*)(ws + FLAG_OFF));
    persist_k<<<256, NTHR, 0, stream>>>(ws, d_out, vp, rho, damp, wav,
                                        src_x, src_z, rcv_x, rcv_z);
}

// Round 13
// 2541.229 us; speedup vs baseline: 1.1263x; 1.1263x over previous
//
#include <hip/hip_runtime.h>
#include <hip/hip_bf16.h>
#include <stdint.h>

// Persistent time-skewed acoustic FD, round 13.
// = round 11 arithmetic (3 coeff arrays, packed f32) + __launch_bounds__(1024,4)
// so the allocator gets 128 VGPRs/wave (16 waves/CU = our exact occupancy) and
// the persistent coeff/state arrays stop spilling to scratch (round 12's
// symmetric FETCH/WRITE growth). Keeps refresh skips + last-publish skip.

#define NXd 512
#define NZd 512
#define NTd 1000
#define Sd  2
#define Rd  512
#define C1f 1.125f
#define C2f (-1.0f/24.0f)
#define CVXf 1e-4f              // DT/DX
#define SRC_AMPf 1e-5f          // DT/(DX*DZ)

#define TZ 32
#define TX 64
#define KSTEPS 7
#define NWIN 143                // 142*7 + 6 = 1000
#define Hz 32
#define Hx 32
#define RLZ 96                  // TZ + 2*Hz
#define RLX 128                 // TX + 2*Hx
#define ZB 3                    // rows per thread
#define NZBLK 32                // RLZ/ZB
#define NTHR 1024               // NZBLK*32

#define NN  (NZd*NXd)
#define FSZ (Sd*NN)
#define BUF_SZ (3*FSZ)
#define FLAG_OFF (2*BUF_SZ)
#define BAR_OFF  (2*BUF_SZ + 32)
#define WS_NEED_FLOATS (2*BUF_SZ + 32 + 160)
#define WS_NEED_BYTES ((size_t)WS_NEED_FLOATS * 4)

typedef float vf4 __attribute__((ext_vector_type(4)));

__device__ __forceinline__ vf4 ld4(const float* p) { return *(const vf4*)p; }
__device__ __forceinline__ void st4(float* p, vf4 v) { *(vf4*)p = v; }

// write-through 16B store: lands at the coherence point, no dirty L2 line.
__device__ __forceinline__ void st4_wt(float* p, vf4 v) {
    asm volatile("global_store_dwordx4 %0, %1, off sc0 sc1" :: "v"(p), "v"(v) : "memory");
}
__device__ __forceinline__ void st1_wt(float* p, float v) {
    asm volatile("global_store_dword %0, %1, off sc0 sc1" :: "v"(p), "v"(v) : "memory");
}
__device__ __forceinline__ void sth_wt(void* p, unsigned short bits) {
    unsigned u = bits;
    asm volatile("global_store_short %0, %1, off sc0 sc1" :: "v"(p), "v"(u) : "memory");
}

// DPP wave shifts (verified round 5): wave_shr:1 (0x138) = value from lane-1,
// wave_shl:1 (0x130) = value from lane+1. bound_ctrl -> 0 at wave edge.
__device__ __forceinline__ float sh_up1(float v) {
    return __int_as_float(__builtin_amdgcn_update_dpp(
        0, __float_as_int(v), 0x138, 0xF, 0xF, true));
}
__device__ __forceinline__ float sh_dn1(float v) {
    return __int_as_float(__builtin_amdgcn_update_dpp(
        0, __float_as_int(v), 0x130, 0xF, 0xF, true));
}

__global__ void detect_k(const uint32_t* __restrict__ vp_raw, int* __restrict__ flag) {
    int lane = threadIdx.x;
    uint32_t u = vp_raw[lane];
    int hb = (u >> 8) & 0xFF;
    int is_exp = (hb == 0x44 || hb == 0x45) ? 1 : 0;
    unsigned long long m = __ballot(is_exp);
    if (lane == 0) *flag = (__popcll(m) >= 48) ? 1 : 0;
}

__device__ __forceinline__ float load_in(const void* p, int i, int bf) {
    return bf ? __bfloat162float(((const __hip_bfloat16*)p)[i])
              : ((const float*)p)[i];
}

// Monotonic grid barrier (round-7 verified): relaxed tree arrival (data is
// already at coherence point), acquire fence (buffer_inv only) on wake.
__device__ __forceinline__ void gbar(unsigned* __restrict__ bar, int wg, int w) {
    __syncthreads();
    if (threadIdx.x == 0) {
        unsigned* gcnt = bar + (wg & 7) * 16;
        unsigned* mcnt = bar + 128;
        unsigned* gen  = bar + 144;
        unsigned tgt = (unsigned)(w + 1);
        unsigned a = __hip_atomic_fetch_add(gcnt, 1u, __ATOMIC_RELAXED, __HIP_MEMORY_SCOPE_AGENT);
        if (a == 32u * tgt - 1u) {
            unsigned m = __hip_atomic_fetch_add(mcnt, 1u, __ATOMIC_RELAXED, __HIP_MEMORY_SCOPE_AGENT);
            if (m == 8u * tgt - 1u) {
                __hip_atomic_store(gen, tgt, __ATOMIC_RELEASE, __HIP_MEMORY_SCOPE_AGENT);
            }
        }
        for (int it = 0; it < 300000; ++it) {
            if (__hip_atomic_load(gen, __ATOMIC_RELAXED, __HIP_MEMORY_SCOPE_AGENT) >= tgt) break;
            __builtin_amdgcn_s_sleep(2);
        }
        __builtin_amdgcn_fence(__ATOMIC_ACQUIRE, "agent");
    }
    __syncthreads();
}

__global__ __launch_bounds__(NTHR, 4) void persist_k(float* __restrict__ ws,
        void* __restrict__ out, const void* __restrict__ vp,
        const void* __restrict__ rho, const void* __restrict__ damp,
        const void* __restrict__ wav,
        const int* __restrict__ sxp, const int* __restrict__ szp,
        const int* __restrict__ rxp, const int* __restrict__ rzp) {
    __shared__ float lp [RLZ*RLX];           // 48 KB: all p rows
    __shared__ float lvz[RLZ*RLX];           // 48 KB: all vz rows
    __shared__ float lwv[KSTEPS];            // window waveform samples
    // 96+ KB -> 1 WG/CU, co-residency for the barrier

    const int tid  = threadIdx.x;
    const int xg   = tid & 31;
    const int zblk = tid >> 5;               // 0..31
    const int zb0  = zblk * ZB;
    const int xo   = xg * 4;

    const int wg  = blockIdx.x;
    const int xcd = wg & 7;
    const int ii  = wg >> 3;
    const int s   = ii >> 4;
    const int loc = ii & 15;
    const int tz0 = ((xcd >> 1) * 4 + (loc >> 2)) * TZ;
    const int tx0 = ((xcd & 1) * 4 + (loc & 3)) * TX;
    const int bf  = *(const int*)(ws + FLAG_OFF);
    unsigned* bar = (unsigned*)(ws + BAR_OFF);

    const int rxv = (tid < Rd) ? rxp[tid] : 0;
    const int rzv = (tid < Rd) ? rzp[tid] : -1000;
    const bool own = (tid < Rd) && (rzv >= tz0 && rzv < tz0 + TZ &&
                                    rxv >= tx0 && rxv < tx0 + TX);
    const int lrcv = (rzv - tz0 + Hz) * RLX + (rxv - tx0 + Hx);
    const int sxv = sxp[s], szv = szp[s];

    // clamped cross-block row indices (region edges tolerate garbage)
    const int zPm  = (zb0 - 1 < 0) ? 0 : zb0 - 1;
    const int zPn0 = (zb0 + ZB     > RLZ - 1) ? RLZ - 1 : zb0 + ZB;
    const int zPn1 = (zb0 + ZB + 1 > RLZ - 1) ? RLZ - 1 : zb0 + ZB + 1;
    const int zVm2 = (zb0 - 2 < 0) ? 0 : zb0 - 2;
    const int zVm1 = zPm;
    const int zVn0 = zPn0;

    const vf4 zero4 = {0.f, 0.f, 0.f, 0.f};

    // ---- coefficients: loaded once, register-resident for the whole run
    vf4 Ca[ZB], Cb[ZB], Cq[ZB];
    #pragma unroll
    for (int r = 0; r < ZB; ++r) {
        int gz = tz0 - Hz + zb0 + r;
        int gx = tx0 - Hx + xo;
        vf4 a = zero4, b = zero4, q = zero4;
        if (gz >= 0 && gz < NZd) {
            #pragma unroll
            for (int c = 0; c < 4; ++c) {
                int x = gx + c;
                if (x >= 0 && x < NXd) {
                    int gi = gz * NXd + x;
                    float v  = load_in(vp,  gi, bf);
                    float rr = load_in(rho, gi, bf);
                    float d  = load_in(damp, gi, bf);
                    ((float*)&a)[c] = d;
                    ((float*)&b)[c] = d * (CVXf / rr);
                    ((float*)&q)[c] = d * (CVXf * rr * v * v);
                }
            }
        }
        Ca[r] = a; Cb[r] = b; Cq[r] = q;
    }

    vf4 Pv[ZB], Vx[ZB], Vz[ZB];
    #pragma unroll
    for (int r = 0; r < ZB; ++r) { Pv[r] = zero4; Vx[r] = zero4; Vz[r] = zero4; }

    for (int w = 0; w < NWIN; ++w) {
        const int kk = (NTd - w * KSTEPS < KSTEPS) ? (NTd - w * KSTEPS) : KSTEPS;
        const float* bR = ws + (w & 1) * BUF_SZ;
        float*       bW = ws + ((w + 1) & 1) * BUF_SZ;
        const float* rp  = bR + s * NN;
        const float* rvx = bR + FSZ + s * NN;
        const float* rvz = bR + 2 * FSZ + s * NN;

        // ---- waveform samples for this window -> LDS
        if (tid < kk) lwv[tid] = load_in(wav, s * NTd + w * KSTEPS + tid, bf);

        // ---- halo refresh. Skips: w==0 (state known zero, registers are the
        // state), z-rows with state-margin > 28 (rows 0..3, 92..95 -- provably
        // never read: V-active blocks reach down only to row 4).
        #pragma unroll
        for (int r = 0; r < ZB; ++r) {
            int z = zb0 + r;
            int gz = tz0 - Hz + z;
            int gx = tx0 - Hx + xo;
            bool intile = (z >= Hz && z < Hz + TZ && xo >= Hx && xo < Hx + TX);
            if (!intile) {
                bool in = (w > 0) && (z >= 4) && (z < RLZ - 4) &&
                          (gz >= 0) && (gz < NZd) && (gx >= 0) && (gx < NXd);
                if (in) {
                    int gi = gz * NXd + gx;
                    Pv[r] = ld4(rp + gi); Vx[r] = ld4(rvx + gi); Vz[r] = ld4(rvz + gi);
                } else if (w == 0) {
                    Pv[r] = zero4; Vx[r] = zero4; Vz[r] = zero4;
                }
            }
            st4(lp + z * RLX + xo, Pv[r]);
        }
        __syncthreads();

        for (int j = 0; j < kk; ++j) {
            const float wv = lwv[j] * SRC_AMPf;

            const int mV = 4 * (kk - 1 - j) + 2;
            const int mP = mV - 2;
            const bool actV = (zb0 + ZB > Hz - mV) && (zb0 < Hz + TZ + mV);
            const bool actP = (zb0 + ZB > Hz - mP) && (zb0 < Hz + TZ + mP);

            // ---------- V phase: vx,vz <- A*v + B*df(p)   [packed f32]
            if (actV) {
                vf4 pPm  = ld4(lp + zPm  * RLX + xo);
                vf4 pNx0 = ld4(lp + zPn0 * RLX + xo);
                vf4 pNx1 = ld4(lp + zPn1 * RLX + xo);
                #pragma unroll
                for (int r = 0; r < ZB; ++r) {
                    vf4 c = Pv[r];
                    float pmw = sh_up1(c.w);
                    float ppx = sh_dn1(c.x);
                    float ppy = sh_dn1(c.y);
                    vf4 xm1 = __builtin_shufflevector(c, c, 0, 0, 1, 2); xm1.x = pmw;
                    vf4 xp1 = __builtin_shufflevector(c, c, 1, 2, 3, 3); xp1.w = ppx;
                    vf4 xp2 = __builtin_shufflevector(c, c, 2, 3, 3, 3); xp2.z = ppx; xp2.w = ppy;
                    vf4 pzm = (r == 0) ? pPm : Pv[(r == 0) ? 0 : r - 1];
                    vf4 pz1 = (r == ZB-1) ? pNx0 : Pv[(r == ZB-1) ? ZB-1 : r + 1];
                    vf4 pz2 = (r == ZB-2) ? pNx0 : ((r == ZB-1) ? pNx1 : Pv[(r >= ZB-2) ? ZB-1 : r + 2]);
                    vf4 dfx = (xp1 - c) * C1f + (xp2 - xm1) * C2f;
                    vf4 dfz = (pz1 - c) * C1f + (pz2 - pzm) * C2f;
                    Vx[r] = Ca[r] * Vx[r] + Cb[r] * dfx;
                    Vz[r] = Ca[r] * Vz[r] + Cb[r] * dfz;
                    st4(lvz + (zb0 + r) * RLX + xo, Vz[r]);
                }
            }
            __syncthreads();

            // ---------- P phase: p <- A*p + Q*(dbx(vx)+dbz(vz)) [+ source]
            if (actP) {
                vf4 vm2 = ld4(lvz + zVm2 * RLX + xo);
                vf4 vm1 = ld4(lvz + zVm1 * RLX + xo);
                vf4 vn0 = ld4(lvz + zVn0 * RLX + xo);
                #pragma unroll
                for (int r = 0; r < ZB; ++r) {
                    vf4 cx = Vx[r], cz = Vz[r];
                    float vmz = sh_up1(cx.z);
                    float vmw = sh_up1(cx.w);
                    float vpx = sh_dn1(cx.x);
                    vf4 xm1 = __builtin_shufflevector(cx, cx, 0, 0, 1, 2); xm1.x = vmw;
                    vf4 xp1 = __builtin_shufflevector(cx, cx, 1, 2, 3, 3); xp1.w = vpx;
                    vf4 xm2 = __builtin_shufflevector(cx, cx, 0, 0, 0, 1); xm2.x = vmz; xm2.y = vmw;
                    vf4 zm2 = (r == 0) ? vm2 : ((r == 1) ? vm1 : Vz[(r >= 2) ? r - 2 : 0]);
                    vf4 zm1 = (r == 0) ? vm1 : Vz[(r == 0) ? 0 : r - 1];
                    vf4 zp1 = (r == ZB-1) ? vn0 : Vz[(r == ZB-1) ? ZB-1 : r + 1];
                    vf4 dbx = (cx - xm1) * C1f + (xp1 - xm2) * C2f;
                    vf4 dbz = (cz - zm1) * C1f + (zp1 - zm2) * C2f;
                    Pv[r] = Ca[r] * Pv[r] + Cq[r] * (dbx + dbz);
                    int gz = tz0 - Hz + zb0 + r;
                    if (gz == szv) {
                        int dcol = sxv - (tx0 - Hx + xo);
                        if      (dcol == 0) Pv[r].x += wv;
                        else if (dcol == 1) Pv[r].y += wv;
                        else if (dcol == 2) Pv[r].z += wv;
                        else if (dcol == 3) Pv[r].w += wv;
                    }
                    st4(lp + (zb0 + r) * RLX + xo, Pv[r]);
                }
            }
            __syncthreads();

            if (own) {
                float val = lp[lrcv];
                int oi = (s * NTd + (w * KSTEPS + j)) * Rd + tid;
                if (bf) {
                    __hip_bfloat16 h = __float2bfloat16(val);
                    unsigned short bits; __builtin_memcpy(&bits, &h, 2);
                    sth_wt((__hip_bfloat16*)out + oi, bits);
                } else {
                    st1_wt((float*)out + oi, val);
                }
            }
        }

        // ---- publish tile interior (write-through: no dirty L2 at barrier);
        // skipped at the last window (nobody reads it)
        if (w < NWIN - 1) {
            float* wp  = bW + s * NN;
            float* wvx = bW + FSZ + s * NN;
            float* wvz = bW + 2 * FSZ + s * NN;
            #pragma unroll
            for (int r = 0; r < ZB; ++r) {
                int z = zb0 + r;
                if (z >= Hz && z < Hz + TZ && xo >= Hx && xo < Hx + TX) {
                    int gi = (tz0 - Hz + z) * NXd + (tx0 - Hx + xo);
                    st4_wt(wp + gi, Pv[r]);
                    st4_wt(wvx + gi, Vx[r]);
                    st4_wt(wvz + gi, Vz[r]);
                }
            }
            gbar(bar, wg, w);
        }
    }
}

extern "C" void kernel_launch(void* const* d_in, const int* in_sizes, int n_in,
                              void* d_out, int out_size, void* d_ws, size_t ws_size,
                              hipStream_t stream) {
    if (ws_size < WS_NEED_BYTES) return;
    float* ws = (float*)d_ws;
    const void* vp   = d_in[0];
    const void* rho  = d_in[1];
    const void* damp = d_in[2];
    const void* wav  = d_in[3];
    const int* src_x = (const int*)d_in[4];
    const int* src_z = (const int*)d_in[5];
    const int* rcv_x = (const int*)d_in[6];
    const int* rcv_z = (const int*)d_in[7];

    hipMemsetAsync(ws, 0, WS_NEED_BYTES, stream);
    detect_k<<<1, 64, 0, stream>>>((const uint32_t*)vp, (int*)(ws + FLAG_OFF));
    persist_k<<<256, NTHR, 0, stream>>>(ws, d_out, vp, rho, damp, wav,
                                        src_x, src_z, rcv_x, rcv_z);
}